// Round 1
// baseline (136.094 us; speedup 1.0000x reference)
//
#include <hip/hip_runtime.h>
#include <hip/hip_fp16.h>

// Problem constants (fixed by the reference)
constexpr int B_  = 8;
constexpr int LQ  = 8192;
constexpr int LK  = 1024;
constexpr int NF  = 64;
constexpr int PAD = 8;            // f16 pad (16 B) to break LDS bank strides
constexpr int LDW = NF + PAD;     // 72 f16 per row = 144 B (9*16, keeps b128 alignment)

typedef _Float16 f16x8 __attribute__((ext_vector_type(8)));
typedef float    f32x4 __attribute__((ext_vector_type(4)));

#define MFMA16(a, b, c) __builtin_amdgcn_mfma_f32_16x16x32_f16((a), (b), (c), 0, 0, 0)

__device__ __forceinline__ f16x8 cvt8(const float* p) {
  // p is 32B-aligned by construction (multiples of 8 floats from a 256B-aligned row)
  float4 a = ((const float4*)p)[0];
  float4 b = ((const float4*)p)[1];
  f16x8 r;
  r[0] = (_Float16)a.x; r[1] = (_Float16)a.y; r[2] = (_Float16)a.z; r[3] = (_Float16)a.w;
  r[4] = (_Float16)b.x; r[5] = (_Float16)b.y; r[6] = (_Float16)b.z; r[7] = (_Float16)b.w;
  return r;
}

__device__ __forceinline__ f16x8 ldf(const _Float16* p) {
  return *(const f16x8*)p;   // ds_read_b128 / global_load_dwordx4 when aligned
}

// ---------------------------------------------------------------------------
// Kernel A: K = kv @ Wk  -> f16 [b][key][d]   (row-major == B^T layout for QK^T)
//           V = kv @ Wv  -> f16 [b][d][key]   (transposed == B^T layout for PV)
// grid = B * (LK/64) = 128 blocks, 256 threads (4 waves x 16 rows)
// ---------------------------------------------------------------------------
__global__ __launch_bounds__(256) void kv_proj_kernel(
    const float* __restrict__ kv, const float* __restrict__ Wk,
    const float* __restrict__ Wv, _Float16* __restrict__ Kb,
    _Float16* __restrict__ Vt) {
  __shared__ __align__(16) _Float16 wkT[NF][LDW];  // wkT[d][e] = Wk[e][d]
  __shared__ __align__(16) _Float16 wvT[NF][LDW];

  const int t    = threadIdx.x;
  const int wave = t >> 6, lane = t & 63, g = lane >> 4, c = lane & 15;
  const int b    = blockIdx.x >> 4;        // LK/64 = 16 tiles per batch
  const int key_base = (blockIdx.x & 15) * 64;

  // Stage W^T (once per block; transient bank conflicts are negligible here)
#pragma unroll
  for (int i = 0; i < 16; ++i) {
    int idx = t + 256 * i;                 // 4096 elements
    int e = idx >> 6, d = idx & 63;
    wkT[d][e] = (_Float16)Wk[idx];
    wvT[d][e] = (_Float16)Wv[idx];
  }
  __syncthreads();

  // A-frags of kv rows: m = c (local row), k = g*8 + j (+32 for second k-step)
  const int row = key_base + wave * 16 + c;
  const float* src = kv + ((size_t)b * LK + row) * NF;
  f16x8 a0 = cvt8(src + g * 8);
  f16x8 a1 = cvt8(src + 32 + g * 8);

#pragma unroll
  for (int nb = 0; nb < 4; ++nb) {
    f32x4 kacc = {0.f, 0.f, 0.f, 0.f};
    f32x4 vacc = {0.f, 0.f, 0.f, 0.f};
    const _Float16* wk0 = &wkT[nb * 16 + c][g * 8];
    const _Float16* wv0 = &wvT[nb * 16 + c][g * 8];
    kacc = MFMA16(a0, ldf(wk0),      kacc);
    kacc = MFMA16(a1, ldf(wk0 + 32), kacc);
    vacc = MFMA16(a0, ldf(wv0),      vacc);
    vacc = MFMA16(a1, ldf(wv0 + 32), vacc);
    // C-layout: row = g*4 + r (local), col = nb*16 + c (feature d)
#pragma unroll
    for (int r = 0; r < 4; ++r) {
      int krow = key_base + wave * 16 + g * 4 + r;
      Kb[((size_t)b * LK + krow) * NF + nb * 16 + c] = (_Float16)kacc[r];
      Vt[((size_t)b * NF + nb * 16 + c) * LK + krow] = (_Float16)vacc[r];
    }
  }
}

// ---------------------------------------------------------------------------
// Kernel B: fused Q projection + flash attention.
// grid = B * (LQ/64) = 1024 blocks, 256 threads (4 waves x 16 q-rows each).
// Flash loop over 16 key-tiles of 64; K/V tiles staged in LDS, shared by waves.
// ---------------------------------------------------------------------------
__global__ __launch_bounds__(256) void attn_kernel(
    const float* __restrict__ x, const float* __restrict__ Wq,
    const _Float16* __restrict__ Kb, const _Float16* __restrict__ Vt,
    float* __restrict__ out) {
  __shared__ __align__(16) _Float16 wqT[NF][LDW];       // 9216 B
  __shared__ __align__(16) _Float16 ks[64][LDW];        // 9216 B  K tile [key][d]
  __shared__ __align__(16) _Float16 vs[NF][LDW];        // 9216 B  V^T tile [d][key]
  __shared__ __align__(16) _Float16 ps[4][16][LDW];     // 9216 B  per-wave P scratch

  const int t    = threadIdx.x;
  const int wave = t >> 6, lane = t & 63, g = lane >> 4, c = lane & 15;
  const int b    = blockIdx.x >> 7;        // LQ/64 = 128 q-tiles per batch
  const int q_base = (blockIdx.x & 127) * 64;

#pragma unroll
  for (int i = 0; i < 16; ++i) {
    int idx = t + 256 * i;
    wqT[idx & 63][idx >> 6] = (_Float16)Wq[idx];
  }
  __syncthreads();

  // ---- Q = x @ Wq for this wave's 16 rows (A-frags straight from global) ----
  const float* xrow = x + ((size_t)b * LQ + q_base + wave * 16 + c) * NF;
  f16x8 xa0 = cvt8(xrow + g * 8);
  f16x8 xa1 = cvt8(xrow + 32 + g * 8);
#pragma unroll
  for (int nb = 0; nb < 4; ++nb) {
    f32x4 qacc = {0.f, 0.f, 0.f, 0.f};
    const _Float16* wq0 = &wqT[nb * 16 + c][g * 8];
    qacc = MFMA16(xa0, ldf(wq0),      qacc);
    qacc = MFMA16(xa1, ldf(wq0 + 32), qacc);
#pragma unroll
    for (int r = 0; r < 4; ++r)
      ps[wave][g * 4 + r][nb * 16 + c] = (_Float16)qacc[r];  // C-layout -> LDS
  }
  // Re-read as A-operand fragments (stay in registers for the whole K loop)
  f16x8 qa0 = ldf(&ps[wave][c][g * 8]);
  f16x8 qa1 = ldf(&ps[wave][c][32 + g * 8]);

  float m_r[4], l_r[4];
  f32x4 oacc[4];
#pragma unroll
  for (int r = 0; r < 4; ++r) { m_r[r] = -1e30f; l_r[r] = 0.f; }
#pragma unroll
  for (int nb = 0; nb < 4; ++nb) oacc[nb] = {0.f, 0.f, 0.f, 0.f};

  const _Float16* Kg = Kb + (size_t)b * LK * NF;
  const _Float16* Vg = Vt + (size_t)b * NF * LK;
  constexpr float LOG2E = 1.44269504088896f;

  for (int tile = 0; tile < 16; ++tile) {
    __syncthreads();   // previous iteration's LDS reads complete
    {
      // K tile: 64x64 f16 = 8 KB contiguous; 32 B per thread
      int srow = t >> 2, scol = (t & 3) * 16;
      const float4* kp = (const float4*)(Kg + (size_t)(tile * 64) * NF + t * 16);
      float4 k0 = kp[0], k1 = kp[1];
      *(float4*)&ks[srow][scol]     = k0;
      *(float4*)&ks[srow][scol + 8] = k1;
      // V^T tile: 64 rows of 128 B, row stride LK*2 in global
      const float4* vp = (const float4*)(Vg + (size_t)srow * LK + tile * 64 + scol);
      float4 v0 = vp[0], v1 = vp[1];
      *(float4*)&vs[srow][scol]     = v0;
      *(float4*)&vs[srow][scol + 8] = v1;
    }
    __syncthreads();

    // ---- S = Q K^T  (C-layout: row = g*4+r, col/key = nb*16+c) ----
    f32x4 s[4];
#pragma unroll
    for (int nb = 0; nb < 4; ++nb) {
      s[nb] = {0.f, 0.f, 0.f, 0.f};
      const _Float16* kf = &ks[nb * 16 + c][g * 8];
      s[nb] = MFMA16(qa0, ldf(kf),      s[nb]);
      s[nb] = MFMA16(qa1, ldf(kf + 32), s[nb]);
    }

    // ---- online softmax across this tile's 64 keys ----
    float tmax[4];
#pragma unroll
    for (int r = 0; r < 4; ++r)
      tmax[r] = fmaxf(fmaxf(s[0][r], s[1][r]), fmaxf(s[2][r], s[3][r]));
#pragma unroll
    for (int off = 1; off < 16; off <<= 1)
#pragma unroll
      for (int r = 0; r < 4; ++r)
        tmax[r] = fmaxf(tmax[r], __shfl_xor(tmax[r], off));

    float alpha[4], rsum[4];
#pragma unroll
    for (int r = 0; r < 4; ++r) {
      float mnew = fmaxf(m_r[r], tmax[r]);
      alpha[r] = __builtin_amdgcn_exp2f((m_r[r] - mnew) * LOG2E);
      m_r[r] = mnew;
      rsum[r] = 0.f;
    }
#pragma unroll
    for (int nb = 0; nb < 4; ++nb)
#pragma unroll
      for (int r = 0; r < 4; ++r) {
        float p = __builtin_amdgcn_exp2f((s[nb][r] - m_r[r]) * LOG2E);
        s[nb][r] = p;
        rsum[r] += p;
      }
#pragma unroll
    for (int off = 1; off < 16; off <<= 1)
#pragma unroll
      for (int r = 0; r < 4; ++r)
        rsum[r] += __shfl_xor(rsum[r], off);
#pragma unroll
    for (int r = 0; r < 4; ++r) l_r[r] = l_r[r] * alpha[r] + rsum[r];
#pragma unroll
    for (int nb = 0; nb < 4; ++nb)
#pragma unroll
      for (int r = 0; r < 4; ++r) oacc[nb][r] *= alpha[r];

    // ---- P: C-layout -> LDS -> A-layout (m120 verified transform) ----
#pragma unroll
    for (int nb = 0; nb < 4; ++nb)
#pragma unroll
      for (int r = 0; r < 4; ++r)
        ps[wave][g * 4 + r][nb * 16 + c] = (_Float16)s[nb][r];
    f16x8 pa0 = ldf(&ps[wave][c][g * 8]);
    f16x8 pa1 = ldf(&ps[wave][c][32 + g * 8]);

    // ---- O += P V  (B = V^T tile in vs) ----
#pragma unroll
    for (int nb = 0; nb < 4; ++nb) {
      const _Float16* vf = &vs[nb * 16 + c][g * 8];
      oacc[nb] = MFMA16(pa0, ldf(vf),      oacc[nb]);
      oacc[nb] = MFMA16(pa1, ldf(vf + 32), oacc[nb]);
    }
  }

  // ---- epilogue: O / l, fp32 store ----
  float inv[4];
#pragma unroll
  for (int r = 0; r < 4; ++r) inv[r] = 1.0f / l_r[r];
#pragma unroll
  for (int nb = 0; nb < 4; ++nb)
#pragma unroll
    for (int r = 0; r < 4; ++r)
      out[((size_t)b * LQ + q_base + wave * 16 + g * 4 + r) * NF + nb * 16 + c] =
          oacc[nb][r] * inv[r];
}

extern "C" void kernel_launch(void* const* d_in, const int* in_sizes, int n_in,
                              void* d_out, int out_size, void* d_ws, size_t ws_size,
                              hipStream_t stream) {
  const float* x  = (const float*)d_in[0];
  const float* kv = (const float*)d_in[1];
  const float* Wq = (const float*)d_in[2];
  const float* Wk = (const float*)d_in[3];
  const float* Wv = (const float*)d_in[4];
  float* out = (float*)d_out;

  _Float16* Kb = (_Float16*)d_ws;                  // [B][LK][NF] f16 = 1 MB
  _Float16* Vt = Kb + (size_t)B_ * LK * NF;        // [B][NF][LK] f16 = 1 MB

  kv_proj_kernel<<<B_ * (LK / 64), 256, 0, stream>>>(kv, Wk, Wv, Kb, Vt);
  attn_kernel<<<B_ * (LQ / 64), 256, 0, stream>>>(x, Wq, Kb, Vt, out);
}

// Round 2
// 113.960 us; speedup vs baseline: 1.1942x; 1.1942x over previous
//
#include <hip/hip_runtime.h>
#include <hip/hip_fp16.h>

constexpr int B_  = 8;
constexpr int LQ  = 8192;
constexpr int LK  = 1024;
constexpr int NF  = 64;
constexpr int PAD = 8;
constexpr int LDW = NF + PAD;     // 72 f16 = 144 B rows

typedef _Float16 f16x8 __attribute__((ext_vector_type(8)));
typedef _Float16 f16x4 __attribute__((ext_vector_type(4)));
typedef float    f32x4 __attribute__((ext_vector_type(4)));

#define MFMA16(a, b, c) __builtin_amdgcn_mfma_f32_16x16x32_f16((a), (b), (c), 0, 0, 0)

__device__ __forceinline__ f16x8 cvt8(const float* p) {
  float4 a = ((const float4*)p)[0];
  float4 b = ((const float4*)p)[1];
  f16x8 r;
  r[0] = (_Float16)a.x; r[1] = (_Float16)a.y; r[2] = (_Float16)a.z; r[3] = (_Float16)a.w;
  r[4] = (_Float16)b.x; r[5] = (_Float16)b.y; r[6] = (_Float16)b.z; r[7] = (_Float16)b.w;
  return r;
}

__device__ __forceinline__ f16x8 ldf(const _Float16* p) { return *(const f16x8*)p; }

// Packed f32x4 -> f16x4 store (2x v_cvt_pkrtz + one ds_write_b64)
__device__ __forceinline__ void st_pk4(_Float16* dst, float a, float b, float c, float d) {
  auto lo = __builtin_amdgcn_cvt_pkrtz(a, b);
  auto hi = __builtin_amdgcn_cvt_pkrtz(c, d);
  auto v  = __builtin_shufflevector(lo, hi, 0, 1, 2, 3);
  *(decltype(v)*)dst = v;
}

// ---------------------------------------------------------------------------
// Kernel A: K = kv@Wk -> f16 [b][key][d];  V = kv@Wv -> f16 [b][d][key].
// K computed transposed (A=Wk^T, B=kv^T) so C-layout packs along d -> b64 LDS
// writes; V computed direct (packs along key). Coalesced float4 global stores.
// grid = B*(LK/64) = 128 blocks x 256 threads.
// ---------------------------------------------------------------------------
__global__ __launch_bounds__(256) void kv_proj_kernel(
    const float* __restrict__ kv, const float* __restrict__ Wk,
    const float* __restrict__ Wv, _Float16* __restrict__ Kb,
    _Float16* __restrict__ Vt) {
  __shared__ __align__(16) _Float16 wkT[NF][LDW];
  __shared__ __align__(16) _Float16 wvT[NF][LDW];
  __shared__ __align__(16) _Float16 ktile[64][LDW];   // [key][d]
  __shared__ __align__(16) _Float16 vtileT[64][LDW];  // [d][key]

  const int t    = threadIdx.x;
  const int wave = t >> 6, lane = t & 63, g = lane >> 4, c = lane & 15;
  const int b    = blockIdx.x >> 4;
  const int key_base = (blockIdx.x & 15) * 64;

#pragma unroll
  for (int i = 0; i < 16; ++i) {
    int idx = t + 256 * i;
    int e = idx >> 6, d = idx & 63;
    wkT[d][e] = (_Float16)Wk[idx];
    wvT[d][e] = (_Float16)Wv[idx];
  }

  // kv row fragments: serve as B-frag (for K^T) AND A-frag (for V)
  const float* src = kv + ((size_t)b * LK + key_base + wave * 16 + c) * NF;
  f16x8 a0 = cvt8(src + g * 8);
  f16x8 a1 = cvt8(src + 32 + g * 8);
  __syncthreads();

#pragma unroll
  for (int mb = 0; mb < 4; ++mb) {
    // K^T: A = Wk^T (rows d), B = kv^T (cols = this wave's 16 keys)
    f32x4 kacc = {0.f, 0.f, 0.f, 0.f};
    const _Float16* wk0 = &wkT[mb * 16 + c][g * 8];
    kacc = MFMA16(ldf(wk0),      a0, kacc);
    kacc = MFMA16(ldf(wk0 + 32), a1, kacc);
    // C: row = d = mb*16+g*4+r, col = key(local16) = c  -> pack along d
    st_pk4(&ktile[wave * 16 + c][mb * 16 + g * 4], kacc[0], kacc[1], kacc[2], kacc[3]);

    // V: A = kv rows, B = Wv  -> C: row = key = g*4+r, col = d = mb*16+c
    f32x4 vacc = {0.f, 0.f, 0.f, 0.f};
    const _Float16* wv0 = &wvT[mb * 16 + c][g * 8];
    vacc = MFMA16(a0, ldf(wv0),      vacc);
    vacc = MFMA16(a1, ldf(wv0 + 32), vacc);
    // pack along key into V^T tile
    st_pk4(&vtileT[mb * 16 + c][wave * 16 + g * 4], vacc[0], vacc[1], vacc[2], vacc[3]);
  }
  __syncthreads();

  // Coalesced stores: 256 threads x 32 B each
  const int srow = t >> 2, scol = (t & 3) * 16;
  {
    float4* kd = (float4*)(Kb + ((size_t)b * LK + key_base + srow) * NF + scol);
    kd[0] = *(float4*)&ktile[srow][scol];
    kd[1] = *(float4*)&ktile[srow][scol + 8];
    float4* vd = (float4*)(Vt + ((size_t)b * NF + srow) * LK + key_base + scol);
    vd[0] = *(float4*)&vtileT[srow][scol];
    vd[1] = *(float4*)&vtileT[srow][scol + 8];
  }
}

// ---------------------------------------------------------------------------
// Kernel B: fused Q projection + flash attention, S^T orientation.
// S^T = K·Q^T: each lane owns 16 keys of ONE query (q = lane&15) -> scalar
// softmax state, 2-step shuffle reductions, b64-packed P round-trip.
// grid = B*(LQ/64) = 1024 blocks x 256 threads (4 waves x 16 queries).
// ---------------------------------------------------------------------------
__global__ __launch_bounds__(256) void attn_kernel(
    const float* __restrict__ x, const float* __restrict__ Wq,
    const _Float16* __restrict__ Kb, const _Float16* __restrict__ Vt,
    float* __restrict__ out) {
  __shared__ __align__(16) _Float16 wqT[NF][LDW];   // Wq^T, pre-scaled by LOG2E
  __shared__ __align__(16) _Float16 ks[64][LDW];    // K tile [key][d]
  __shared__ __align__(16) _Float16 vs[64][LDW];    // V^T tile [d][key]
  __shared__ __align__(16) _Float16 ps[4][16][LDW]; // per-wave Q/P scratch [q][*]

  const int t    = threadIdx.x;
  const int wave = t >> 6, lane = t & 63, g = lane >> 4, c = lane & 15;
  const int b    = blockIdx.x >> 7;
  const int q_base = (blockIdx.x & 127) * 64;
  constexpr float LOG2E = 1.44269504088896f;

#pragma unroll
  for (int i = 0; i < 16; ++i) {
    int idx = t + 256 * i;
    wqT[idx & 63][idx >> 6] = (_Float16)(Wq[idx] * LOG2E);  // fold softmax log2-scale
  }

  const float* xrow = x + ((size_t)b * LQ + q_base + wave * 16 + c) * NF;
  f16x8 xa0 = cvt8(xrow + g * 8);
  f16x8 xa1 = cvt8(xrow + 32 + g * 8);

  const _Float16* Kg = Kb + (size_t)b * LK * NF;
  const _Float16* Vg = Vt + (size_t)b * NF * LK;
  const int srow = t >> 2, scol = (t & 3) * 16;

  // Prefetch tile 0 into registers while Q-proj runs
  float4 kp0, kp1, vp0, vp1;
  {
    const float4* kp = (const float4*)(Kg + (size_t)t * 16);
    kp0 = kp[0]; kp1 = kp[1];
    const float4* vp = (const float4*)(Vg + (size_t)srow * LK + scol);
    vp0 = vp[0]; vp1 = vp[1];
  }
  __syncthreads();  // wqT ready

  // Q^T = Wq^T · x^T  (A = Wq^T frags from LDS, B = x row frags)
#pragma unroll
  for (int mb = 0; mb < 4; ++mb) {
    f32x4 qacc = {0.f, 0.f, 0.f, 0.f};
    const _Float16* wq0 = &wqT[mb * 16 + c][g * 8];
    qacc = MFMA16(ldf(wq0),      xa0, qacc);
    qacc = MFMA16(ldf(wq0 + 32), xa1, qacc);
    // C: row = d = mb*16+g*4+r, col = q = c -> pack along d
    st_pk4(&ps[wave][c][mb * 16 + g * 4], qacc[0], qacc[1], qacc[2], qacc[3]);
  }
  // B-frags of Q for S^T (same bytes as A-frags of Q would be)
  f16x8 qb0 = ldf(&ps[wave][c][g * 8]);
  f16x8 qb1 = ldf(&ps[wave][c][32 + g * 8]);

  float m_s = -1e30f, l_s = 0.f;
  f32x4 oacc[4];
#pragma unroll
  for (int nb = 0; nb < 4; ++nb) oacc[nb] = {0.f, 0.f, 0.f, 0.f};

  for (int tile = 0; tile < 16; ++tile) {
    __syncthreads();  // previous tile's LDS reads complete
    *(f16x8*)&ks[srow][scol]     = *(f16x8*)&kp0;
    *(f16x8*)&ks[srow][scol + 8] = *(f16x8*)&kp1;
    *(f16x8*)&vs[srow][scol]     = *(f16x8*)&vp0;
    *(f16x8*)&vs[srow][scol + 8] = *(f16x8*)&vp1;
    __syncthreads();  // tile staged
    if (tile < 15) {  // prefetch next tile; latency overlaps compute below
      const float4* kp = (const float4*)(Kg + (size_t)(tile + 1) * 64 * NF + t * 16);
      kp0 = kp[0]; kp1 = kp[1];
      const float4* vp = (const float4*)(Vg + (size_t)srow * LK + (tile + 1) * 64 + scol);
      vp0 = vp[0]; vp1 = vp[1];
    }

    // ---- S^T = K·Q^T: lane (g,c) -> query c, keys kb*16+g*4+r ----
    f32x4 st[4];
#pragma unroll
    for (int kb = 0; kb < 4; ++kb) {
      st[kb] = {0.f, 0.f, 0.f, 0.f};
      const _Float16* kf = &ks[kb * 16 + c][g * 8];
      st[kb] = MFMA16(ldf(kf),      qb0, st[kb]);
      st[kb] = MFMA16(ldf(kf + 32), qb1, st[kb]);
    }

    // ---- online softmax (per-lane scalar state, query = c) ----
    float tmax = st[0][0];
#pragma unroll
    for (int kb = 0; kb < 4; ++kb)
#pragma unroll
      for (int r = 0; r < 4; ++r) tmax = fmaxf(tmax, st[kb][r]);
    tmax = fmaxf(tmax, __shfl_xor(tmax, 16));
    tmax = fmaxf(tmax, __shfl_xor(tmax, 32));

    float mnew  = fmaxf(m_s, tmax);
    float alpha = __builtin_amdgcn_exp2f(m_s - mnew);
    m_s = mnew;

    float rsum = 0.f;
#pragma unroll
    for (int kb = 0; kb < 4; ++kb)
#pragma unroll
      for (int r = 0; r < 4; ++r) {
        float p = __builtin_amdgcn_exp2f(st[kb][r] - mnew);
        st[kb][r] = p;
        rsum += p;
      }
    rsum += __shfl_xor(rsum, 16);
    rsum += __shfl_xor(rsum, 32);
    l_s = l_s * alpha + rsum;

    // broadcast alpha for O's rows (row q = g*4+r lives in lane q for g'=0)
    float aq[4];
#pragma unroll
    for (int r = 0; r < 4; ++r) aq[r] = __shfl(alpha, 4 * g + r);
#pragma unroll
    for (int nb = 0; nb < 4; ++nb)
#pragma unroll
      for (int r = 0; r < 4; ++r) oacc[nb][r] *= aq[r];

    // ---- P: pack b64 into per-wave scratch, reread as A-frags ----
#pragma unroll
    for (int kb = 0; kb < 4; ++kb)
      st_pk4(&ps[wave][c][kb * 16 + g * 4], st[kb][0], st[kb][1], st[kb][2], st[kb][3]);
    f16x8 pa0 = ldf(&ps[wave][c][g * 8]);
    f16x8 pa1 = ldf(&ps[wave][c][32 + g * 8]);

    // ---- O += P·V ----
#pragma unroll
    for (int nb = 0; nb < 4; ++nb) {
      const _Float16* vf = &vs[nb * 16 + c][g * 8];
      oacc[nb] = MFMA16(pa0, ldf(vf),      oacc[nb]);
      oacc[nb] = MFMA16(pa1, ldf(vf + 32), oacc[nb]);
    }
  }

  // ---- epilogue ----
  float linv = 1.0f / l_s;
  float lq[4];
#pragma unroll
  for (int r = 0; r < 4; ++r) lq[r] = __shfl(linv, 4 * g + r);
#pragma unroll
  for (int nb = 0; nb < 4; ++nb)
#pragma unroll
    for (int r = 0; r < 4; ++r)
      out[((size_t)b * LQ + q_base + wave * 16 + g * 4 + r) * NF + nb * 16 + c] =
          oacc[nb][r] * lq[r];
}

extern "C" void kernel_launch(void* const* d_in, const int* in_sizes, int n_in,
                              void* d_out, int out_size, void* d_ws, size_t ws_size,
                              hipStream_t stream) {
  const float* x  = (const float*)d_in[0];
  const float* kv = (const float*)d_in[1];
  const float* Wq = (const float*)d_in[2];
  const float* Wk = (const float*)d_in[3];
  const float* Wv = (const float*)d_in[4];
  float* out = (float*)d_out;

  _Float16* Kb = (_Float16*)d_ws;
  _Float16* Vt = Kb + (size_t)B_ * LK * NF;

  kv_proj_kernel<<<B_ * (LK / 64), 256, 0, stream>>>(kv, Wk, Wv, Kb, Vt);
  attn_kernel<<<B_ * (LQ / 64), 256, 0, stream>>>(x, Wq, Kb, Vt, out);
}

// Round 3
// 110.643 us; speedup vs baseline: 1.2300x; 1.0300x over previous
//
#include <hip/hip_runtime.h>
#include <hip/hip_fp16.h>

constexpr int B_  = 8;
constexpr int LQ  = 8192;
constexpr int LK  = 1024;
constexpr int NF  = 64;
constexpr int PAD = 8;
constexpr int LDW = NF + PAD;     // 72 f16 = 144 B rows

typedef _Float16 f16x8 __attribute__((ext_vector_type(8)));
typedef float    f32x4 __attribute__((ext_vector_type(4)));

#define MFMA16(a, b, c) __builtin_amdgcn_mfma_f32_16x16x32_f16((a), (b), (c), 0, 0, 0)

__device__ __forceinline__ f16x8 cvt8(const float* p) {
  float4 a = ((const float4*)p)[0];
  float4 b = ((const float4*)p)[1];
  f16x8 r;
  r[0] = (_Float16)a.x; r[1] = (_Float16)a.y; r[2] = (_Float16)a.z; r[3] = (_Float16)a.w;
  r[4] = (_Float16)b.x; r[5] = (_Float16)b.y; r[6] = (_Float16)b.z; r[7] = (_Float16)b.w;
  return r;
}

__device__ __forceinline__ f16x8 ldf(const _Float16* p) { return *(const f16x8*)p; }

__device__ __forceinline__ void st_pk4(_Float16* dst, float a, float b, float c, float d) {
  auto lo = __builtin_amdgcn_cvt_pkrtz(a, b);
  auto hi = __builtin_amdgcn_cvt_pkrtz(c, d);
  auto v  = __builtin_shufflevector(lo, hi, 0, 1, 2, 3);
  *(decltype(v)*)dst = v;
}

// C-regs (f32x4 u = blocks 2h+0, v = 2h+1) -> one A/B-frag half (8 f16).
// Maps MFMA C-layout register order onto A-frag k-order given the baked
// position permutation: position [h g g a r r] holds logical [h a g g r r].
__device__ __forceinline__ f16x8 pack8(f32x4 u, f32x4 v) {
  auto a = __builtin_amdgcn_cvt_pkrtz(u[0], u[1]);
  auto b = __builtin_amdgcn_cvt_pkrtz(u[2], u[3]);
  auto cc = __builtin_amdgcn_cvt_pkrtz(v[0], v[1]);
  auto d = __builtin_amdgcn_cvt_pkrtz(v[2], v[3]);
  f16x8 r;
  r[0] = a[0]; r[1] = a[1]; r[2] = b[0];  r[3] = b[1];
  r[4] = cc[0]; r[5] = cc[1]; r[6] = d[0]; r[7] = d[1];
  return r;
}

// ---------------------------------------------------------------------------
// Kernel A: K = kv@Wk -> f16 [b][key][d-permuted]; V = kv@Wv -> [b][d][key-permuted].
// The column permutation (pos 8h+2g+a <- logical group 4*(2h+a)+g) lets the attn
// kernel convert MFMA C-regs directly into A/B-fragments in-lane (no LDS trip).
// grid = B*(LK/64) = 128 blocks x 256 threads.
// ---------------------------------------------------------------------------
__global__ __launch_bounds__(256) void kv_proj_kernel(
    const float* __restrict__ kv, const float* __restrict__ Wk,
    const float* __restrict__ Wv, _Float16* __restrict__ Kb,
    _Float16* __restrict__ Vt) {
  __shared__ __align__(16) _Float16 wkT[NF][LDW];
  __shared__ __align__(16) _Float16 wvT[NF][LDW];
  __shared__ __align__(16) _Float16 ktile[64][LDW];   // [key][d-pos]
  __shared__ __align__(16) _Float16 vtileT[64][LDW];  // [d][key-pos]

  const int t    = threadIdx.x;
  const int wave = t >> 6, lane = t & 63, g = lane >> 4, c = lane & 15;
  const int b    = blockIdx.x >> 4;
  const int key_base = (blockIdx.x & 15) * 64;

#pragma unroll
  for (int i = 0; i < 16; ++i) {
    int idx = t + 256 * i;
    int e = idx >> 6, d = idx & 63;
    wkT[d][e] = (_Float16)Wk[idx];
    wvT[d][e] = (_Float16)Wv[idx];
  }

  const float* src = kv + ((size_t)b * LK + key_base + wave * 16 + c) * NF;
  f16x8 a0 = cvt8(src + g * 8);
  f16x8 a1 = cvt8(src + 32 + g * 8);
  __syncthreads();

#pragma unroll
  for (int mb = 0; mb < 4; ++mb) {
    // K^T: A = Wk^T, B = kv^T -> C rows = d = 16mb+4g+r, col = key = c
    f32x4 kacc = {0.f, 0.f, 0.f, 0.f};
    const _Float16* wk0 = &wkT[mb * 16 + c][g * 8];
    kacc = MFMA16(ldf(wk0),      a0, kacc);
    kacc = MFMA16(ldf(wk0 + 32), a1, kacc);
    // permuted column position for feature group (mb,g)
    st_pk4(&ktile[wave * 16 + c][(8 * (mb >> 1) + 2 * g + (mb & 1)) * 4],
           kacc[0], kacc[1], kacc[2], kacc[3]);

    // V: A = kv rows, B = Wv -> C rows = key = 16*wave+4g+r, col = d = 16mb+c
    f32x4 vacc = {0.f, 0.f, 0.f, 0.f};
    const _Float16* wv0 = &wvT[mb * 16 + c][g * 8];
    vacc = MFMA16(a0, ldf(wv0),      vacc);
    vacc = MFMA16(a1, ldf(wv0 + 32), vacc);
    // permuted key position for key group (wave,g)
    st_pk4(&vtileT[mb * 16 + c][(8 * (wave >> 1) + 2 * g + (wave & 1)) * 4],
           vacc[0], vacc[1], vacc[2], vacc[3]);
  }
  __syncthreads();

  const int srow = t >> 2, scol = (t & 3) * 16;
  {
    float4* kd = (float4*)(Kb + ((size_t)b * LK + key_base + srow) * NF + scol);
    kd[0] = *(float4*)&ktile[srow][scol];
    kd[1] = *(float4*)&ktile[srow][scol + 8];
    float4* vd = (float4*)(Vt + ((size_t)b * NF + srow) * LK + key_base + scol);
    vd[0] = *(float4*)&vtileT[srow][scol];
    vd[1] = *(float4*)&vtileT[srow][scol + 8];
  }
}

// ---------------------------------------------------------------------------
// Kernel B: fused Q-proj + flash attention. 2 waves x 32 queries = 64 q/block,
// grid = 1024 blocks x 128 threads. K/V tiles in LDS (18.4 KB -> 8 blocks/CU);
// Q and P never touch LDS (in-lane C-reg -> frag repack via baked permutation).
// ---------------------------------------------------------------------------
__global__ __launch_bounds__(128, 4) void attn_kernel(
    const float* __restrict__ x, const float* __restrict__ Wq,
    const _Float16* __restrict__ Kb, const _Float16* __restrict__ Vt,
    float* __restrict__ out) {
  __shared__ __align__(16) _Float16 ks[64][LDW];   // K tile; holds Wq^T during Q-proj
  __shared__ __align__(16) _Float16 vs[64][LDW];   // V^T tile

  const int t    = threadIdx.x;
  const int wave = t >> 6, lane = t & 63, g = lane >> 4, c = lane & 15;
  const int b    = blockIdx.x >> 7;
  const int q_base = (blockIdx.x & 127) * 64;
  constexpr float LOG2E = 1.44269504088896f;

  // Stage Wq^T (log2e-folded) into the ks region
#pragma unroll
  for (int i = 0; i < 32; ++i) {
    int idx = t + 128 * i;
    ks[idx & 63][idx >> 6] = (_Float16)(Wq[idx] * LOG2E);
  }

  const _Float16* Kg = Kb + (size_t)b * LK * NF;
  const _Float16* Vg = Vt + (size_t)b * NF * LK;
  const int srow = t >> 1, shalf = t & 1;   // staging: row, 64B half

  // Prefetch K tile 0 while Wq stages / Q-proj runs
  f16x8 kpre[4];
  {
    const f16x8* kp = (const f16x8*)(Kg + srow * NF + shalf * 32);
    kpre[0] = kp[0]; kpre[1] = kp[1]; kpre[2] = kp[2]; kpre[3] = kp[3];
  }
  __syncthreads();  // Wq^T ready

  // Q^T = Wq^T · x^T, subtile-serial; C-regs -> B-frags in-lane
  f16x8 qb[2][2];
#pragma unroll
  for (int s = 0; s < 2; ++s) {
    const float* xrow = x + ((size_t)b * LQ + q_base + wave * 32 + s * 16 + c) * NF;
    f16x8 xa0 = cvt8(xrow + g * 8);
    f16x8 xa1 = cvt8(xrow + 32 + g * 8);
    f32x4 qa[4];
#pragma unroll
    for (int mb = 0; mb < 4; ++mb) {
      qa[mb] = {0.f, 0.f, 0.f, 0.f};
      const _Float16* wq0 = &ks[mb * 16 + c][g * 8];
      qa[mb] = MFMA16(ldf(wq0),      xa0, qa[mb]);
      qa[mb] = MFMA16(ldf(wq0 + 32), xa1, qa[mb]);
    }
    qb[s][0] = pack8(qa[0], qa[1]);
    qb[s][1] = pack8(qa[2], qa[3]);
  }
  __syncthreads();  // Q-proj reads done; ks free for K tiles

  float m_s[2] = {-1e30f, -1e30f}, l_s[2] = {0.f, 0.f};
  f32x4 oacc[2][4];
#pragma unroll
  for (int s = 0; s < 2; ++s)
#pragma unroll
    for (int nb = 0; nb < 4; ++nb) oacc[s][nb] = {0.f, 0.f, 0.f, 0.f};

  for (int tile = 0; tile < 16; ++tile) {
    // stage K (prefetched) + V
    *(f16x8*)&ks[srow][shalf * 32]      = kpre[0];
    *(f16x8*)&ks[srow][shalf * 32 + 8]  = kpre[1];
    *(f16x8*)&ks[srow][shalf * 32 + 16] = kpre[2];
    *(f16x8*)&ks[srow][shalf * 32 + 24] = kpre[3];
    {
      const f16x8* vp = (const f16x8*)(Vg + (size_t)srow * LK + tile * 64 + shalf * 32);
      f16x8 v0 = vp[0], v1 = vp[1], v2 = vp[2], v3 = vp[3];
      *(f16x8*)&vs[srow][shalf * 32]      = v0;
      *(f16x8*)&vs[srow][shalf * 32 + 8]  = v1;
      *(f16x8*)&vs[srow][shalf * 32 + 16] = v2;
      *(f16x8*)&vs[srow][shalf * 32 + 24] = v3;
    }
    __syncthreads();  // tile staged
    if (tile < 15) {
      const f16x8* kp = (const f16x8*)(Kg + (size_t)(tile + 1) * 64 * NF + srow * NF + shalf * 32);
      kpre[0] = kp[0]; kpre[1] = kp[1]; kpre[2] = kp[2]; kpre[3] = kp[3];
    }

    // ---- S^T = K·Q^T for both q-subtiles; K-frags read once ----
    f32x4 st[2][4];
#pragma unroll
    for (int kb = 0; kb < 4; ++kb) {
      const _Float16* kf = &ks[kb * 16 + c][g * 8];
      f16x8 k0 = ldf(kf), k1 = ldf(kf + 32);
      st[0][kb] = {0.f, 0.f, 0.f, 0.f};
      st[1][kb] = {0.f, 0.f, 0.f, 0.f};
      st[0][kb] = MFMA16(k0, qb[0][0], st[0][kb]);
      st[0][kb] = MFMA16(k1, qb[0][1], st[0][kb]);
      st[1][kb] = MFMA16(k0, qb[1][0], st[1][kb]);
      st[1][kb] = MFMA16(k1, qb[1][1], st[1][kb]);
    }

    // ---- online softmax per subtile (scalar state; query = s*16+c) ----
    f16x8 pa[2][2];
#pragma unroll
    for (int s = 0; s < 2; ++s) {
      float tmax = st[s][0][0];
#pragma unroll
      for (int kb = 0; kb < 4; ++kb)
#pragma unroll
        for (int r = 0; r < 4; ++r) tmax = fmaxf(tmax, st[s][kb][r]);
      tmax = fmaxf(tmax, __shfl_xor(tmax, 16));
      tmax = fmaxf(tmax, __shfl_xor(tmax, 32));

      if (__ballot(tmax > m_s[s]) != 0) {  // wave-uniform: rescale only if max grew
        float mnew  = fmaxf(m_s[s], tmax);
        float alpha = __builtin_amdgcn_exp2f(m_s[s] - mnew);
        m_s[s] = mnew;
        l_s[s] *= alpha;
        float aq[4];
#pragma unroll
        for (int r = 0; r < 4; ++r) aq[r] = __shfl(alpha, 4 * g + r);
#pragma unroll
        for (int nb = 0; nb < 4; ++nb)
#pragma unroll
          for (int r = 0; r < 4; ++r) oacc[s][nb][r] *= aq[r];
      }

      float rsum = 0.f;
#pragma unroll
      for (int kb = 0; kb < 4; ++kb)
#pragma unroll
        for (int r = 0; r < 4; ++r) {
          float p = __builtin_amdgcn_exp2f(st[s][kb][r] - m_s[s]);
          st[s][kb][r] = p;
          rsum += p;
        }
      rsum += __shfl_xor(rsum, 16);
      rsum += __shfl_xor(rsum, 32);
      l_s[s] += rsum;

      // C-regs -> A-frags in-lane (permutation-matched to vs columns)
      pa[s][0] = pack8(st[s][0], st[s][1]);
      pa[s][1] = pack8(st[s][2], st[s][3]);
    }

    // ---- O += P·V; V-frags read once, shared across subtiles ----
#pragma unroll
    for (int nb = 0; nb < 4; ++nb) {
      const _Float16* vf = &vs[nb * 16 + c][g * 8];
      f16x8 v0 = ldf(vf), v1 = ldf(vf + 32);
      oacc[0][nb] = MFMA16(pa[0][0], v0, oacc[0][nb]);
      oacc[0][nb] = MFMA16(pa[0][1], v1, oacc[0][nb]);
      oacc[1][nb] = MFMA16(pa[1][0], v0, oacc[1][nb]);
      oacc[1][nb] = MFMA16(pa[1][1], v1, oacc[1][nb]);
    }
    __syncthreads();  // frag reads done; next iteration may overwrite
  }

  // ---- epilogue ----
#pragma unroll
  for (int s = 0; s < 2; ++s) {
    float linv = 1.0f / l_s[s];
    float lq[4];
#pragma unroll
    for (int r = 0; r < 4; ++r) lq[r] = __shfl(linv, 4 * g + r);
#pragma unroll
    for (int nb = 0; nb < 4; ++nb)
#pragma unroll
      for (int r = 0; r < 4; ++r)
        out[((size_t)b * LQ + q_base + wave * 32 + s * 16 + 4 * g + r) * NF + nb * 16 + c] =
            oacc[s][nb][r] * lq[r];
  }
}

extern "C" void kernel_launch(void* const* d_in, const int* in_sizes, int n_in,
                              void* d_out, int out_size, void* d_ws, size_t ws_size,
                              hipStream_t stream) {
  const float* x  = (const float*)d_in[0];
  const float* kv = (const float*)d_in[1];
  const float* Wq = (const float*)d_in[2];
  const float* Wk = (const float*)d_in[3];
  const float* Wv = (const float*)d_in[4];
  float* out = (float*)d_out;

  _Float16* Kb = (_Float16*)d_ws;
  _Float16* Vt = Kb + (size_t)B_ * LK * NF;

  kv_proj_kernel<<<B_ * (LK / 64), 256, 0, stream>>>(kv, Wk, Wv, Kb, Vt);
  attn_kernel<<<B_ * (LQ / 64), 128, 0, stream>>>(x, Wq, Kb, Vt, out);
}